// Round 7
// baseline (277.451 us; speedup 1.0000x reference)
//
#include <hip/hip_runtime.h>

// B=2, N=64, D=256, H=8, DK=32.  ROWS = B*N*N = 8192.
#define ROWS 8192
#define DIM  256

typedef short short8 __attribute__((ext_vector_type(8)));
typedef float f4     __attribute__((ext_vector_type(4)));

__device__ __forceinline__ float bf2f(unsigned int u16) {
    union { unsigned int i; float f; } v;
    v.i = (u16 & 0xffffu) << 16;
    return v.f;
}
__device__ __forceinline__ unsigned short f2bf(float f) {
    union { float f; unsigned int u; } v; v.f = f;
    unsigned int r = v.u + 0x7fffu + ((v.u >> 16) & 1u);   // RNE
    return (unsigned short)(r >> 16);
}

// ---------------------------------------------------------------------------
// Merged casts. Blocks [0,2048): x(8192x256 fp32)->xb bf16.
// Blocks [2048,2624): weights -> WT[n][k] bf16 packed.
//   w0..w4 at w*65536 ; W1(256x512)->512x256 @327680 ; W2(512x256)->256x512 @458752
// ---------------------------------------------------------------------------
__global__ __launch_bounds__(256)
void cast_all(const float* __restrict__ x, unsigned short* __restrict__ xb,
              const float* __restrict__ w0, const float* __restrict__ w1,
              const float* __restrict__ w2, const float* __restrict__ w3,
              const float* __restrict__ w4, const float* __restrict__ w5,
              const float* __restrict__ w6, unsigned short* __restrict__ wt)
{
    if (blockIdx.x < 2048) {
        const size_t i = ((size_t)blockIdx.x * 256 + threadIdx.x) * 4;
        float4 v = *(const float4*)(x + i);
        uint2 p;
        p.x = f2bf(v.x) | ((unsigned int)f2bf(v.y) << 16);
        p.y = f2bf(v.z) | ((unsigned int)f2bf(v.w) << 16);
        *(uint2*)(xb + i) = p;
        return;
    }
    __shared__ float t[32][33];
    int id = blockIdx.x - 2048;
    const float* src; int K, N, Ntiles; size_t doff;
    if (id < 320) {
        int w = id >> 6; id &= 63; K = 256; N = 256; Ntiles = 8;
        doff = (size_t)w * 65536;
        src = (w == 0) ? w0 : (w == 1) ? w1 : (w == 2) ? w2 : (w == 3) ? w3 : w4;
    } else if (id < 448) {
        id -= 320; K = 256; N = 512; Ntiles = 16; doff = 327680; src = w5;
    } else {
        id -= 448; K = 512; N = 256; Ntiles = 8;  doff = 458752; src = w6;
    }
    const int tk = id / Ntiles, tn = id % Ntiles;
    const int k0 = tk * 32, n0 = tn * 32;
    const int c = threadIdx.x & 31, r8 = threadIdx.x >> 5;
    for (int rr = r8; rr < 32; rr += 8)
        t[rr][c] = src[(size_t)(k0 + rr) * N + n0 + c];
    __syncthreads();
    for (int rr = r8; rr < 32; rr += 8)
        wt[doff + (size_t)(n0 + rr) * K + k0 + c] = f2bf(t[c][rr]);
}

// ---------------------------------------------------------------------------
// Projection MFMA GEMM with head-major scatter epilogue.
//   wsel 0 (lk): dst[b][h][x=i][a=j][d]   wsel 1 (rk): dst[b][h][a=i][y=j][d]
//   wsel 2 (lv): dst[b][h][x=i][a=j][d]   wsel 3 (rv): dst[b][h][y=j][a=i][d]
// grid = (16, 64)
// ---------------------------------------------------------------------------
__global__ __launch_bounds__(256)
void proj_mfma(const unsigned short* __restrict__ A, const unsigned short* __restrict__ WT,
               unsigned short* __restrict__ projT)
{
    const int lane = threadIdx.x & 63, wave = threadIdx.x >> 6;
    const int wsel = blockIdx.x >> 2;
    const int col0 = (blockIdx.x & 3) * 64;
    const int m0 = blockIdx.y * 128 + wave * 32;
    const int lm = lane & 15, lk8 = (lane >> 4) * 8;
    const unsigned short* W = WT + (size_t)wsel * 65536;
    unsigned short* dst = projT + (size_t)wsel * 2097152;

    f4 acc[2][4];
    #pragma unroll
    for (int i = 0; i < 2; ++i)
        #pragma unroll
        for (int j = 0; j < 4; ++j) acc[i][j] = (f4){0.f, 0.f, 0.f, 0.f};

    for (int kc = 0; kc < 256; kc += 32) {
        short8 af[2], bf[4];
        #pragma unroll
        for (int i = 0; i < 2; ++i)
            af[i] = *(const short8*)(A + (size_t)(m0 + i * 16 + lm) * 256 + kc + lk8);
        #pragma unroll
        for (int j = 0; j < 4; ++j)
            bf[j] = *(const short8*)(W + (size_t)(col0 + j * 16 + lm) * 256 + kc + lk8);
        #pragma unroll
        for (int i = 0; i < 2; ++i)
            #pragma unroll
            for (int j = 0; j < 4; ++j)
                acc[i][j] = __builtin_amdgcn_mfma_f32_16x16x32_bf16(af[i], bf[j], acc[i][j], 0, 0, 0);
    }

    const int rbase = (lane >> 4) * 4;
    const int swap = (wsel == 3);
    #pragma unroll
    for (int i = 0; i < 2; ++i)
        #pragma unroll
        for (int j = 0; j < 4; ++j) {
            const int c = col0 + j * 16 + lm;
            const int h = c >> 5, d = c & 31;
            #pragma unroll
            for (int r = 0; r < 4; ++r) {
                const int m = m0 + i * 16 + rbase + r;
                const int b = m >> 12, ii = (m >> 6) & 63, jj = m & 63;
                const int p = swap ? jj : ii;
                const int q = swap ? ii : jj;
                const size_t idx = ((((size_t)b * 8 + h) * 64 + p) * 64 + q) * 32 + d;
                dst[idx] = f2bf(acc[i][j][r]);
            }
        }
}

// ---------------------------------------------------------------------------
// Fused triangle attention, block per (b,h,x), 512 threads (8 waves).
// lkT/lvT: [b][h][x][a][d], rkT: [b][h][a][y][d], rvT: [b][h][y][a][d]
// attT[y][a] (pad 68) so exp and aggregation read/write b128 over a.
// obuf[(b*64+x)*64+y][h*32+d] bf16.  grid = 1024.
// ---------------------------------------------------------------------------
__global__ __launch_bounds__(512, 8)
void attn_fused(const unsigned short* __restrict__ lkT, const unsigned short* __restrict__ rkT,
                const unsigned short* __restrict__ lvT, const unsigned short* __restrict__ rvT,
                unsigned short* __restrict__ obuf)
{
    __shared__ float attT[64][68];           // [y][a], padded
    __shared__ unsigned short lkU[64][32];   // raw bf16
    __shared__ unsigned short lvU[64][32];   // raw bf16
    __shared__ float smx[8][64], ssm[8][64];
    __shared__ float mxf[64], invL[64];
    const int bi = blockIdx.x;
    const int b = bi >> 9, h = (bi >> 6) & 7, x = bi & 63;
    const size_t bh = (size_t)b * 8 + h;
    const int tid = threadIdx.x;

    {   // stage lk[x], lv[x]: 2048 bf16 each, 4 per thread (uint2)
        const int a = tid >> 3, d0 = (tid & 7) * 4;
        const size_t off = ((bh * 64 + x) * 64 + a) * 32 + d0;
        *(uint2*)&lkU[a][d0] = *(const uint2*)(lkT + off);
        *(uint2*)&lvU[a][d0] = *(const uint2*)(lvT + off);
    }
    __syncthreads();

    {   // scores: thread (y, az), a = az*8 + k
        const int y = tid & 63, az = tid >> 6;
        float mx = -1e30f;
        #pragma unroll
        for (int k = 0; k < 8; ++k) {
            const int a = az * 8 + k;
            const unsigned short* rp = rkT + ((bh * 64 + a) * 64 + y) * 32;
            float acc = 0.f;
            #pragma unroll
            for (int t = 0; t < 4; ++t) {
                uint4 lk4 = *(const uint4*)&lkU[a][t * 8];
                uint4 rk4 = *(const uint4*)(rp + t * 8);
                acc += bf2f(lk4.x) * bf2f(rk4.x) + bf2f(lk4.x >> 16) * bf2f(rk4.x >> 16)
                     + bf2f(lk4.y) * bf2f(rk4.y) + bf2f(lk4.y >> 16) * bf2f(rk4.y >> 16)
                     + bf2f(lk4.z) * bf2f(rk4.z) + bf2f(lk4.z >> 16) * bf2f(rk4.z >> 16)
                     + bf2f(lk4.w) * bf2f(rk4.w) + bf2f(lk4.w >> 16) * bf2f(rk4.w >> 16);
            }
            float v = acc * 0.17677669529663687f;   // 1/sqrt(32)
            attT[y][a] = v;
            mx = fmaxf(mx, v);
        }
        smx[az][y] = mx;
    }
    __syncthreads();
    if (tid < 64) {
        float m = smx[0][tid];
        #pragma unroll
        for (int j = 1; j < 8; ++j) m = fmaxf(m, smx[j][tid]);
        mxf[tid] = m;
    }
    __syncthreads();

    {   // exp + partial sums: thread (y, az) owns a = az*8..az*8+7 (2x b128)
        const int y = tid & 63, az = tid >> 6;
        const float mx = mxf[y];
        float4 e0 = *(float4*)&attT[y][az * 8];
        float4 e1 = *(float4*)&attT[y][az * 8 + 4];
        e0.x = __expf(e0.x - mx); e0.y = __expf(e0.y - mx);
        e0.z = __expf(e0.z - mx); e0.w = __expf(e0.w - mx);
        e1.x = __expf(e1.x - mx); e1.y = __expf(e1.y - mx);
        e1.z = __expf(e1.z - mx); e1.w = __expf(e1.w - mx);
        *(float4*)&attT[y][az * 8]     = e0;
        *(float4*)&attT[y][az * 8 + 4] = e1;
        ssm[az][y] = e0.x + e0.y + e0.z + e0.w + e1.x + e1.y + e1.z + e1.w;
    }
    __syncthreads();
    if (tid < 64) {
        float s = ssm[0][tid];
        #pragma unroll
        for (int j = 1; j < 8; ++j) s += ssm[j][tid];
        invL[tid] = 1.f / s;
    }
    __syncthreads();

    {   // aggregation: thread (y = tid>>3, dq = tid&7), 4 d's each
        const int y = tid >> 3, d0 = (tid & 7) * 4;
        float o0 = 0.f, o1 = 0.f, o2 = 0.f, o3 = 0.f;
        const unsigned short* rvr = rvT + (bh * 64 + y) * 2048 + d0;
        for (int a4 = 0; a4 < 64; a4 += 4) {
            float4 w4 = *(const float4*)&attT[y][a4];
            #pragma unroll
            for (int u = 0; u < 4; ++u) {
                const int a = a4 + u;
                const float w = (u == 0) ? w4.x : (u == 1) ? w4.y : (u == 2) ? w4.z : w4.w;
                uint2 lv2 = *(const uint2*)&lvU[a][d0];
                uint2 rv2 = *(const uint2*)(rvr + (size_t)a * 32);
                o0 += (w * bf2f(lv2.x))       * bf2f(rv2.x);
                o1 += (w * bf2f(lv2.x >> 16)) * bf2f(rv2.x >> 16);
                o2 += (w * bf2f(lv2.y))       * bf2f(rv2.y);
                o3 += (w * bf2f(lv2.y >> 16)) * bf2f(rv2.y >> 16);
            }
        }
        const float inv = invL[y];
        uint2 pk;
        pk.x = f2bf(o0 * inv) | ((unsigned int)f2bf(o1 * inv) << 16);
        pk.y = f2bf(o2 * inv) | ((unsigned int)f2bf(o3 * inv) << 16);
        *(uint2*)(obuf + (((size_t)b * 64 + x) * 64 + y) * 256 + h * 32 + d0) = pk;
    }
}

// ---------------------------------------------------------------------------
// FFN1: out = relu( A(8192x256 bf16) @ WT(512x256)^T + bias ), bf16 out.
// 64x64 tiles (wave = 16 rows x 64 cols), grid = (8, 128) = 1024 blocks.
// ---------------------------------------------------------------------------
__global__ __launch_bounds__(256)
void gemm_ffn1(const unsigned short* __restrict__ A, const unsigned short* __restrict__ WT,
               const float* __restrict__ bias, unsigned short* __restrict__ outB)
{
    const int lane = threadIdx.x & 63, wave = threadIdx.x >> 6;
    const int m0 = blockIdx.y * 64 + wave * 16;
    const int col0 = blockIdx.x * 64;
    const int lm = lane & 15, lk8 = (lane >> 4) * 8;
    const int K = 256, N = 512;

    f4 acc[4];
    #pragma unroll
    for (int j = 0; j < 4; ++j) acc[j] = (f4){0.f, 0.f, 0.f, 0.f};

    for (int kc = 0; kc < K; kc += 32) {
        short8 af = *(const short8*)(A + (size_t)(m0 + lm) * K + kc + lk8);
        #pragma unroll
        for (int j = 0; j < 4; ++j) {
            short8 bf = *(const short8*)(WT + (size_t)(col0 + j * 16 + lm) * K + kc + lk8);
            acc[j] = __builtin_amdgcn_mfma_f32_16x16x32_bf16(af, bf, acc[j], 0, 0, 0);
        }
    }

    const int rbase = (lane >> 4) * 4;
    #pragma unroll
    for (int j = 0; j < 4; ++j) {
        const int n = col0 + j * 16 + lm;
        const float bb = bias[n];
        #pragma unroll
        for (int r = 0; r < 4; ++r) {
            const int m = m0 + rbase + r;
            outB[(size_t)m * N + n] = f2bf(fmaxf(acc[j][r] + bb, 0.f));
        }
    }
}

// ---------------------------------------------------------------------------
// Fused GEMM + residual + LayerNorm, 512 threads (8 waves x 32 cols).
// tile: 16 rows x 256 cols; wave w covers cols w*32..+31 (2 MFMA per kc).
//   t = A @ WT^T [+ bias] + resid ;  out = LN(t) * gamma + beta
// mode 0: write outF (fp32) and outB (bf16).  mode 1: write outF only.
// grid = 512 (8192/16).
// ---------------------------------------------------------------------------
__global__ __launch_bounds__(512)
void gemm_ln(const unsigned short* __restrict__ A, const unsigned short* __restrict__ WT,
             const float* __restrict__ bias, const float* __restrict__ resid,
             const float* __restrict__ gamma, const float* __restrict__ beta,
             float* __restrict__ outF, unsigned short* __restrict__ outB,
             int K, int mode)
{
    __shared__ float ps[16][8], pq[16][8];
    const int lane = threadIdx.x & 63, wave = threadIdx.x >> 6;
    const int m0 = blockIdx.x * 16;
    const int col0 = wave * 32;
    const int lm = lane & 15, lk8 = (lane >> 4) * 8;

    f4 acc[2];
    acc[0] = (f4){0.f, 0.f, 0.f, 0.f};
    acc[1] = (f4){0.f, 0.f, 0.f, 0.f};

    for (int kc = 0; kc < K; kc += 32) {
        short8 af = *(const short8*)(A + (size_t)(m0 + lm) * K + kc + lk8);
        #pragma unroll
        for (int j = 0; j < 2; ++j) {
            short8 bf = *(const short8*)(WT + (size_t)(col0 + j * 16 + lm) * K + kc + lk8);
            acc[j] = __builtin_amdgcn_mfma_f32_16x16x32_bf16(af, bf, acc[j], 0, 0, 0);
        }
    }

    const int rbase = (lane >> 4) * 4;
    float v[2][4];
    float s[4] = {0.f, 0.f, 0.f, 0.f}, q[4] = {0.f, 0.f, 0.f, 0.f};
    #pragma unroll
    for (int j = 0; j < 2; ++j) {
        const int n = col0 + j * 16 + lm;
        const float bb = bias ? bias[n] : 0.f;
        #pragma unroll
        for (int r = 0; r < 4; ++r) {
            const int m = m0 + rbase + r;
            float t = acc[j][r] + bb + resid[(size_t)m * 256 + n];
            v[j][r] = t;
            s[r] += t;
            q[r] += t * t;
        }
    }
    #pragma unroll
    for (int off = 1; off < 16; off <<= 1) {
        #pragma unroll
        for (int r = 0; r < 4; ++r) {
            s[r] += __shfl_xor(s[r], off);
            q[r] += __shfl_xor(q[r], off);
        }
    }
    if (lm == 0) {
        #pragma unroll
        for (int r = 0; r < 4; ++r) {
            ps[rbase + r][wave] = s[r];
            pq[rbase + r][wave] = q[r];
        }
    }
    __syncthreads();
    #pragma unroll
    for (int r = 0; r < 4; ++r) {
        const int lr = rbase + r;
        float S = 0.f, Q = 0.f;
        #pragma unroll
        for (int w = 0; w < 8; ++w) { S += ps[lr][w]; Q += pq[lr][w]; }
        const float mu = S * (1.f / 256.f);
        const float ri = rsqrtf(Q * (1.f / 256.f) - mu * mu + 1e-5f);
        const int m = m0 + lr;
        #pragma unroll
        for (int j = 0; j < 2; ++j) {
            const int n = col0 + j * 16 + lm;
            const float rv = (v[j][r] - mu) * ri * gamma[n] + beta[n];
            outF[(size_t)m * 256 + n] = rv;
            if (mode == 0) outB[(size_t)m * 256 + n] = f2bf(rv);
        }
    }
}

// ---------------------------------------------------------------------------
extern "C" void kernel_launch(void* const* d_in, const int* in_sizes, int n_in,
                              void* d_out, int out_size, void* d_ws, size_t ws_size,
                              hipStream_t stream)
{
    const float* x    = (const float*)d_in[0];
    const float* Wlk  = (const float*)d_in[1];
    const float* Wrk  = (const float*)d_in[2];
    const float* Wlv  = (const float*)d_in[3];
    const float* Wrv  = (const float*)d_in[4];
    const float* Wout = (const float*)d_in[5];
    const float* g1   = (const float*)d_in[6];
    const float* be1  = (const float*)d_in[7];
    const float* W1   = (const float*)d_in[8];
    const float* b1   = (const float*)d_in[9];
    const float* W2   = (const float*)d_in[10];
    const float* b2   = (const float*)d_in[11];
    const float* g2   = (const float*)d_in[12];
    const float* be2  = (const float*)d_in[13];

    char* base = (char*)d_ws;
    const size_t MB = 1ull << 20;
    unsigned short* xb    = (unsigned short*)(base + 0);        // 4MB; reused as obuf
    unsigned short* obufb = (unsigned short*)(base + 0);
    unsigned short* projT = (unsigned short*)(base + 4 * MB);   // lkT,rkT,lvT,rvT 4x4MB
    unsigned short* lkT   = projT;
    unsigned short* rkT   = projT + 2097152;
    unsigned short* lvT   = projT + 2 * 2097152;
    unsigned short* rvT   = projT + 3 * 2097152;
    float*          hf    = (float*)(base + 20 * MB);           // 8MB
    unsigned short* hb    = (unsigned short*)(base + 28 * MB);  // 4MB
    unsigned short* midb  = (unsigned short*)(base + 36 * MB);  // 8MB
    unsigned short* WT    = (unsigned short*)(base + 52 * MB);  // 1.2MB

    // 1. casts (x -> bf16, weights -> transposed bf16)
    cast_all<<<2624, 256, 0, stream>>>(x, xb, Wlk, Wrk, Wlv, Wrv, Wout, W1, W2, WT);
    // 2. projections + head-major scatter
    proj_mfma<<<dim3(16, 64), 256, 0, stream>>>(xb, WT, projT);
    // 3. fused scores+softmax+aggregation -> obuf (bf16)
    attn_fused<<<1024, 512, 0, stream>>>(lkT, rkT, lvT, rvT, obufb);
    // 4. h = LN(x + obuf @ W_out) -> hf (fp32) + hb (bf16)
    gemm_ln<<<512, 512, 0, stream>>>(obufb, WT + 262144, nullptr, x, g1, be1, hf, hb, 256, 0);
    // 5. midb = relu(hb @ W1 + b1) (bf16)
    gemm_ffn1<<<dim3(8, 128), 256, 0, stream>>>(hb, WT + 327680, b1, midb);
    // 6. out = LN(hf + midb @ W2 + b2) -> fp32 d_out
    gemm_ln<<<512, 512, 0, stream>>>(midb, WT + 458752, b2, hf, g2, be2, (float*)d_out, nullptr, 512, 1);
}

// Round 8
// 222.444 us; speedup vs baseline: 1.2473x; 1.2473x over previous
//
#include <hip/hip_runtime.h>

// B=2, N=64, D=256, H=8, DK=32.  ROWS = B*N*N = 8192.
#define ROWS 8192
#define DIM  256

typedef short short8 __attribute__((ext_vector_type(8)));
typedef float f4     __attribute__((ext_vector_type(4)));

__device__ __forceinline__ float bf2f(unsigned int u16) {
    union { unsigned int i; float f; } v;
    v.i = (u16 & 0xffffu) << 16;
    return v.f;
}
__device__ __forceinline__ unsigned short f2bf(float f) {
    union { float f; unsigned int u; } v; v.f = f;
    unsigned int r = v.u + 0x7fffu + ((v.u >> 16) & 1u);   // RNE
    return (unsigned short)(r >> 16);
}

// ---------------------------------------------------------------------------
// Merged casts. Blocks [0,2048): x(8192x256 fp32)->xb bf16.
// Blocks [2048,2624): weights -> WT[n][k] bf16 packed.
//   w0..w4 at w*65536 ; W1(256x512)->512x256 @327680 ; W2(512x256)->256x512 @458752
// ---------------------------------------------------------------------------
__global__ __launch_bounds__(256)
void cast_all(const float* __restrict__ x, unsigned short* __restrict__ xb,
              const float* __restrict__ w0, const float* __restrict__ w1,
              const float* __restrict__ w2, const float* __restrict__ w3,
              const float* __restrict__ w4, const float* __restrict__ w5,
              const float* __restrict__ w6, unsigned short* __restrict__ wt)
{
    if (blockIdx.x < 2048) {
        const size_t i = ((size_t)blockIdx.x * 256 + threadIdx.x) * 4;
        float4 v = *(const float4*)(x + i);
        uint2 p;
        p.x = f2bf(v.x) | ((unsigned int)f2bf(v.y) << 16);
        p.y = f2bf(v.z) | ((unsigned int)f2bf(v.w) << 16);
        *(uint2*)(xb + i) = p;
        return;
    }
    __shared__ float t[32][33];
    int id = blockIdx.x - 2048;
    const float* src; int K, N, Ntiles; size_t doff;
    if (id < 320) {
        int w = id >> 6; id &= 63; K = 256; N = 256; Ntiles = 8;
        doff = (size_t)w * 65536;
        src = (w == 0) ? w0 : (w == 1) ? w1 : (w == 2) ? w2 : (w == 3) ? w3 : w4;
    } else if (id < 448) {
        id -= 320; K = 256; N = 512; Ntiles = 16; doff = 327680; src = w5;
    } else {
        id -= 448; K = 512; N = 256; Ntiles = 8;  doff = 458752; src = w6;
    }
    const int tk = id / Ntiles, tn = id % Ntiles;
    const int k0 = tk * 32, n0 = tn * 32;
    const int c = threadIdx.x & 31, r8 = threadIdx.x >> 5;
    for (int rr = r8; rr < 32; rr += 8)
        t[rr][c] = src[(size_t)(k0 + rr) * N + n0 + c];
    __syncthreads();
    for (int rr = r8; rr < 32; rr += 8)
        wt[doff + (size_t)(n0 + rr) * K + k0 + c] = f2bf(t[c][rr]);
}

// ---------------------------------------------------------------------------
// Projection MFMA GEMM with head-major scatter epilogue.
//   wsel 0 (lk): dst[b][h][x=i][a=j][d]   wsel 1 (rk): dst[b][h][a=i][y=j][d]
//   wsel 2 (lv): dst[b][h][x=i][a=j][d]   wsel 3 (rv): dst[b][h][y=j][a=i][d]
// grid = (16, 64)
// ---------------------------------------------------------------------------
__global__ __launch_bounds__(256)
void proj_mfma(const unsigned short* __restrict__ A, const unsigned short* __restrict__ WT,
               unsigned short* __restrict__ projT)
{
    const int lane = threadIdx.x & 63, wave = threadIdx.x >> 6;
    const int wsel = blockIdx.x >> 2;
    const int col0 = (blockIdx.x & 3) * 64;
    const int m0 = blockIdx.y * 128 + wave * 32;
    const int lm = lane & 15, lk8 = (lane >> 4) * 8;
    const unsigned short* W = WT + (size_t)wsel * 65536;
    unsigned short* dst = projT + (size_t)wsel * 2097152;

    f4 acc[2][4];
    #pragma unroll
    for (int i = 0; i < 2; ++i)
        #pragma unroll
        for (int j = 0; j < 4; ++j) acc[i][j] = (f4){0.f, 0.f, 0.f, 0.f};

    for (int kc = 0; kc < 256; kc += 32) {
        short8 af[2], bf[4];
        #pragma unroll
        for (int i = 0; i < 2; ++i)
            af[i] = *(const short8*)(A + (size_t)(m0 + i * 16 + lm) * 256 + kc + lk8);
        #pragma unroll
        for (int j = 0; j < 4; ++j)
            bf[j] = *(const short8*)(W + (size_t)(col0 + j * 16 + lm) * 256 + kc + lk8);
        #pragma unroll
        for (int i = 0; i < 2; ++i)
            #pragma unroll
            for (int j = 0; j < 4; ++j)
                acc[i][j] = __builtin_amdgcn_mfma_f32_16x16x32_bf16(af[i], bf[j], acc[i][j], 0, 0, 0);
    }

    const int rbase = (lane >> 4) * 4;
    const int swap = (wsel == 3);
    #pragma unroll
    for (int i = 0; i < 2; ++i)
        #pragma unroll
        for (int j = 0; j < 4; ++j) {
            const int c = col0 + j * 16 + lm;
            const int h = c >> 5, d = c & 31;
            #pragma unroll
            for (int r = 0; r < 4; ++r) {
                const int m = m0 + i * 16 + rbase + r;
                const int b = m >> 12, ii = (m >> 6) & 63, jj = m & 63;
                const int p = swap ? jj : ii;
                const int q = swap ? ii : jj;
                const size_t idx = ((((size_t)b * 8 + h) * 64 + p) * 64 + q) * 32 + d;
                dst[idx] = f2bf(acc[i][j][r]);
            }
        }
}

// ---------------------------------------------------------------------------
// Fused triangle attention, block per (b,h,x), 512 threads (8 waves).
// __launch_bounds__(512,4): VGPR cap 128 (kernel needs ~48; the round-7
// (512,8) variant forced 32 VGPR -> 144MB scratch spills, 2.2x slower).
// LDS 30KB -> 4 blocks/CU = 32 waves/CU.
// lkT/lvT: [b][h][x][a][d], rkT: [b][h][a][y][d], rvT: [b][h][y][a][d]
// attT[y][a] (pad 68) so exp and aggregation read/write b128 over a.
// obuf[(b*64+x)*64+y][h*32+d] bf16.  grid = 1024.
// ---------------------------------------------------------------------------
__global__ __launch_bounds__(512, 4)
void attn_fused(const unsigned short* __restrict__ lkT, const unsigned short* __restrict__ rkT,
                const unsigned short* __restrict__ lvT, const unsigned short* __restrict__ rvT,
                unsigned short* __restrict__ obuf)
{
    __shared__ float attT[64][68];           // [y][a], padded
    __shared__ unsigned short lkU[64][32];   // raw bf16
    __shared__ unsigned short lvU[64][32];   // raw bf16
    __shared__ float smx[8][64], ssm[8][64];
    __shared__ float mxf[64], invL[64];
    const int bi = blockIdx.x;
    const int b = bi >> 9, h = (bi >> 6) & 7, x = bi & 63;
    const size_t bh = (size_t)b * 8 + h;
    const int tid = threadIdx.x;

    {   // stage lk[x], lv[x]: 2048 bf16 each, 4 per thread (uint2)
        const int a = tid >> 3, d0 = (tid & 7) * 4;
        const size_t off = ((bh * 64 + x) * 64 + a) * 32 + d0;
        *(uint2*)&lkU[a][d0] = *(const uint2*)(lkT + off);
        *(uint2*)&lvU[a][d0] = *(const uint2*)(lvT + off);
    }
    __syncthreads();

    {   // scores: thread (y, az), a = az*8 + k
        const int y = tid & 63, az = tid >> 6;
        float mx = -1e30f;
        #pragma unroll
        for (int k = 0; k < 8; ++k) {
            const int a = az * 8 + k;
            const unsigned short* rp = rkT + ((bh * 64 + a) * 64 + y) * 32;
            float acc = 0.f;
            #pragma unroll
            for (int t = 0; t < 4; ++t) {
                uint4 lk4 = *(const uint4*)&lkU[a][t * 8];
                uint4 rk4 = *(const uint4*)(rp + t * 8);
                acc += bf2f(lk4.x) * bf2f(rk4.x) + bf2f(lk4.x >> 16) * bf2f(rk4.x >> 16)
                     + bf2f(lk4.y) * bf2f(rk4.y) + bf2f(lk4.y >> 16) * bf2f(rk4.y >> 16)
                     + bf2f(lk4.z) * bf2f(rk4.z) + bf2f(lk4.z >> 16) * bf2f(rk4.z >> 16)
                     + bf2f(lk4.w) * bf2f(rk4.w) + bf2f(lk4.w >> 16) * bf2f(rk4.w >> 16);
            }
            float v = acc * 0.17677669529663687f;   // 1/sqrt(32)
            attT[y][a] = v;
            mx = fmaxf(mx, v);
        }
        smx[az][y] = mx;
    }
    __syncthreads();
    if (tid < 64) {
        float m = smx[0][tid];
        #pragma unroll
        for (int j = 1; j < 8; ++j) m = fmaxf(m, smx[j][tid]);
        mxf[tid] = m;
    }
    __syncthreads();

    {   // exp + partial sums: thread (y, az) owns a = az*8..az*8+7 (2x b128)
        const int y = tid & 63, az = tid >> 6;
        const float mx = mxf[y];
        float4 e0 = *(float4*)&attT[y][az * 8];
        float4 e1 = *(float4*)&attT[y][az * 8 + 4];
        e0.x = __expf(e0.x - mx); e0.y = __expf(e0.y - mx);
        e0.z = __expf(e0.z - mx); e0.w = __expf(e0.w - mx);
        e1.x = __expf(e1.x - mx); e1.y = __expf(e1.y - mx);
        e1.z = __expf(e1.z - mx); e1.w = __expf(e1.w - mx);
        *(float4*)&attT[y][az * 8]     = e0;
        *(float4*)&attT[y][az * 8 + 4] = e1;
        ssm[az][y] = e0.x + e0.y + e0.z + e0.w + e1.x + e1.y + e1.z + e1.w;
    }
    __syncthreads();
    if (tid < 64) {
        float s = ssm[0][tid];
        #pragma unroll
        for (int j = 1; j < 8; ++j) s += ssm[j][tid];
        invL[tid] = 1.f / s;
    }
    __syncthreads();

    {   // aggregation: thread (y = tid>>3, dq = tid&7), 4 d's each
        const int y = tid >> 3, d0 = (tid & 7) * 4;
        float o0 = 0.f, o1 = 0.f, o2 = 0.f, o3 = 0.f;
        const unsigned short* rvr = rvT + (bh * 64 + y) * 2048 + d0;
        for (int a4 = 0; a4 < 64; a4 += 4) {
            float4 w4 = *(const float4*)&attT[y][a4];
            #pragma unroll
            for (int u = 0; u < 4; ++u) {
                const int a = a4 + u;
                const float w = (u == 0) ? w4.x : (u == 1) ? w4.y : (u == 2) ? w4.z : w4.w;
                uint2 lv2 = *(const uint2*)&lvU[a][d0];
                uint2 rv2 = *(const uint2*)(rvr + (size_t)a * 32);
                o0 += (w * bf2f(lv2.x))       * bf2f(rv2.x);
                o1 += (w * bf2f(lv2.x >> 16)) * bf2f(rv2.x >> 16);
                o2 += (w * bf2f(lv2.y))       * bf2f(rv2.y);
                o3 += (w * bf2f(lv2.y >> 16)) * bf2f(rv2.y >> 16);
            }
        }
        const float inv = invL[y];
        uint2 pk;
        pk.x = f2bf(o0 * inv) | ((unsigned int)f2bf(o1 * inv) << 16);
        pk.y = f2bf(o2 * inv) | ((unsigned int)f2bf(o3 * inv) << 16);
        *(uint2*)(obuf + (((size_t)b * 64 + x) * 64 + y) * 256 + h * 32 + d0) = pk;
    }
}

// ---------------------------------------------------------------------------
// FFN1: out = relu( A(8192x256 bf16) @ WT(512x256)^T + bias ), bf16 out.
// 64x64 tiles (wave = 16 rows x 64 cols), grid = (8, 128) = 1024 blocks.
// ---------------------------------------------------------------------------
__global__ __launch_bounds__(256)
void gemm_ffn1(const unsigned short* __restrict__ A, const unsigned short* __restrict__ WT,
               const float* __restrict__ bias, unsigned short* __restrict__ outB)
{
    const int lane = threadIdx.x & 63, wave = threadIdx.x >> 6;
    const int m0 = blockIdx.y * 64 + wave * 16;
    const int col0 = blockIdx.x * 64;
    const int lm = lane & 15, lk8 = (lane >> 4) * 8;
    const int K = 256, N = 512;

    f4 acc[4];
    #pragma unroll
    for (int j = 0; j < 4; ++j) acc[j] = (f4){0.f, 0.f, 0.f, 0.f};

    for (int kc = 0; kc < K; kc += 32) {
        short8 af = *(const short8*)(A + (size_t)(m0 + lm) * K + kc + lk8);
        #pragma unroll
        for (int j = 0; j < 4; ++j) {
            short8 bf = *(const short8*)(WT + (size_t)(col0 + j * 16 + lm) * K + kc + lk8);
            acc[j] = __builtin_amdgcn_mfma_f32_16x16x32_bf16(af, bf, acc[j], 0, 0, 0);
        }
    }

    const int rbase = (lane >> 4) * 4;
    #pragma unroll
    for (int j = 0; j < 4; ++j) {
        const int n = col0 + j * 16 + lm;
        const float bb = bias[n];
        #pragma unroll
        for (int r = 0; r < 4; ++r) {
            const int m = m0 + rbase + r;
            outB[(size_t)m * N + n] = f2bf(fmaxf(acc[j][r] + bb, 0.f));
        }
    }
}

// ---------------------------------------------------------------------------
// Fused GEMM + residual + LayerNorm, 512 threads (8 waves x 32 cols).
// tile: 16 rows x 256 cols; wave w covers cols w*32..+31 (2 MFMA per kc).
//   t = A @ WT^T [+ bias] + resid ;  out = LN(t) * gamma + beta
// mode 0: write outF (fp32) and outB (bf16).  mode 1: write outF only.
// grid = 512 (8192/16).
// ---------------------------------------------------------------------------
__global__ __launch_bounds__(512)
void gemm_ln(const unsigned short* __restrict__ A, const unsigned short* __restrict__ WT,
             const float* __restrict__ bias, const float* __restrict__ resid,
             const float* __restrict__ gamma, const float* __restrict__ beta,
             float* __restrict__ outF, unsigned short* __restrict__ outB,
             int K, int mode)
{
    __shared__ float ps[16][8], pq[16][8];
    const int lane = threadIdx.x & 63, wave = threadIdx.x >> 6;
    const int m0 = blockIdx.x * 16;
    const int col0 = wave * 32;
    const int lm = lane & 15, lk8 = (lane >> 4) * 8;

    f4 acc[2];
    acc[0] = (f4){0.f, 0.f, 0.f, 0.f};
    acc[1] = (f4){0.f, 0.f, 0.f, 0.f};

    for (int kc = 0; kc < K; kc += 32) {
        short8 af = *(const short8*)(A + (size_t)(m0 + lm) * K + kc + lk8);
        #pragma unroll
        for (int j = 0; j < 2; ++j) {
            short8 bf = *(const short8*)(WT + (size_t)(col0 + j * 16 + lm) * K + kc + lk8);
            acc[j] = __builtin_amdgcn_mfma_f32_16x16x32_bf16(af, bf, acc[j], 0, 0, 0);
        }
    }

    const int rbase = (lane >> 4) * 4;
    float v[2][4];
    float s[4] = {0.f, 0.f, 0.f, 0.f}, q[4] = {0.f, 0.f, 0.f, 0.f};
    #pragma unroll
    for (int j = 0; j < 2; ++j) {
        const int n = col0 + j * 16 + lm;
        const float bb = bias ? bias[n] : 0.f;
        #pragma unroll
        for (int r = 0; r < 4; ++r) {
            const int m = m0 + rbase + r;
            float t = acc[j][r] + bb + resid[(size_t)m * 256 + n];
            v[j][r] = t;
            s[r] += t;
            q[r] += t * t;
        }
    }
    #pragma unroll
    for (int off = 1; off < 16; off <<= 1) {
        #pragma unroll
        for (int r = 0; r < 4; ++r) {
            s[r] += __shfl_xor(s[r], off);
            q[r] += __shfl_xor(q[r], off);
        }
    }
    if (lm == 0) {
        #pragma unroll
        for (int r = 0; r < 4; ++r) {
            ps[rbase + r][wave] = s[r];
            pq[rbase + r][wave] = q[r];
        }
    }
    __syncthreads();
    #pragma unroll
    for (int r = 0; r < 4; ++r) {
        const int lr = rbase + r;
        float S = 0.f, Q = 0.f;
        #pragma unroll
        for (int w = 0; w < 8; ++w) { S += ps[lr][w]; Q += pq[lr][w]; }
        const float mu = S * (1.f / 256.f);
        const float ri = rsqrtf(Q * (1.f / 256.f) - mu * mu + 1e-5f);
        const int m = m0 + lr;
        #pragma unroll
        for (int j = 0; j < 2; ++j) {
            const int n = col0 + j * 16 + lm;
            const float rv = (v[j][r] - mu) * ri * gamma[n] + beta[n];
            outF[(size_t)m * 256 + n] = rv;
            if (mode == 0) outB[(size_t)m * 256 + n] = f2bf(rv);
        }
    }
}

// ---------------------------------------------------------------------------
extern "C" void kernel_launch(void* const* d_in, const int* in_sizes, int n_in,
                              void* d_out, int out_size, void* d_ws, size_t ws_size,
                              hipStream_t stream)
{
    const float* x    = (const float*)d_in[0];
    const float* Wlk  = (const float*)d_in[1];
    const float* Wrk  = (const float*)d_in[2];
    const float* Wlv  = (const float*)d_in[3];
    const float* Wrv  = (const float*)d_in[4];
    const float* Wout = (const float*)d_in[5];
    const float* g1   = (const float*)d_in[6];
    const float* be1  = (const float*)d_in[7];
    const float* W1   = (const float*)d_in[8];
    const float* b1   = (const float*)d_in[9];
    const float* W2   = (const float*)d_in[10];
    const float* b2   = (const float*)d_in[11];
    const float* g2   = (const float*)d_in[12];
    const float* be2  = (const float*)d_in[13];

    char* base = (char*)d_ws;
    const size_t MB = 1ull << 20;
    unsigned short* xb    = (unsigned short*)(base + 0);        // 4MB; reused as obuf
    unsigned short* obufb = (unsigned short*)(base + 0);
    unsigned short* projT = (unsigned short*)(base + 4 * MB);   // lkT,rkT,lvT,rvT 4x4MB
    unsigned short* lkT   = projT;
    unsigned short* rkT   = projT + 2097152;
    unsigned short* lvT   = projT + 2 * 2097152;
    unsigned short* rvT   = projT + 3 * 2097152;
    float*          hf    = (float*)(base + 20 * MB);           // 8MB
    unsigned short* hb    = (unsigned short*)(base + 28 * MB);  // 4MB
    unsigned short* midb  = (unsigned short*)(base + 36 * MB);  // 8MB
    unsigned short* WT    = (unsigned short*)(base + 52 * MB);  // 1.2MB

    // 1. casts (x -> bf16, weights -> transposed bf16)
    cast_all<<<2624, 256, 0, stream>>>(x, xb, Wlk, Wrk, Wlv, Wrv, Wout, W1, W2, WT);
    // 2. projections + head-major scatter
    proj_mfma<<<dim3(16, 64), 256, 0, stream>>>(xb, WT, projT);
    // 3. fused scores+softmax+aggregation -> obuf (bf16)
    attn_fused<<<1024, 512, 0, stream>>>(lkT, rkT, lvT, rvT, obufb);
    // 4. h = LN(x + obuf @ W_out) -> hf (fp32) + hb (bf16)
    gemm_ln<<<512, 512, 0, stream>>>(obufb, WT + 262144, nullptr, x, g1, be1, hf, hb, 256, 0);
    // 5. midb = relu(hb @ W1 + b1) (bf16)
    gemm_ffn1<<<dim3(8, 128), 256, 0, stream>>>(hb, WT + 327680, b1, midb);
    // 6. out = LN(hf + midb @ W2 + b2) -> fp32 d_out
    gemm_ln<<<512, 512, 0, stream>>>(midb, WT + 458752, b2, hf, g2, be2, (float*)d_out, nullptr, 512, 1);
}

// Round 9
// 193.898 us; speedup vs baseline: 1.4309x; 1.1472x over previous
//
#include <hip/hip_runtime.h>

// B=2, N=64, D=256, H=8, DK=32.  ROWS = B*N*N = 8192.
#define ROWS 8192
#define DIM  256

typedef short short8 __attribute__((ext_vector_type(8)));
typedef float f4     __attribute__((ext_vector_type(4)));

__device__ __forceinline__ float bf2f(unsigned int u16) {
    union { unsigned int i; float f; } v;
    v.i = (u16 & 0xffffu) << 16;
    return v.f;
}
__device__ __forceinline__ unsigned short f2bf(float f) {
    union { float f; unsigned int u; } v; v.f = f;
    unsigned int r = v.u + 0x7fffu + ((v.u >> 16) & 1u);   // RNE
    return (unsigned short)(r >> 16);
}

// ---------------------------------------------------------------------------
// Merged casts. Blocks [0,2048): x(8192x256 fp32)->xb bf16.
// Blocks [2048,2624): weights -> WT[n][k] bf16 packed.
//   w0..w4 at w*65536 ; W1(256x512)->512x256 @327680 ; W2(512x256)->256x512 @458752
// ---------------------------------------------------------------------------
__global__ __launch_bounds__(256)
void cast_all(const float* __restrict__ x, unsigned short* __restrict__ xb,
              const float* __restrict__ w0, const float* __restrict__ w1,
              const float* __restrict__ w2, const float* __restrict__ w3,
              const float* __restrict__ w4, const float* __restrict__ w5,
              const float* __restrict__ w6, unsigned short* __restrict__ wt)
{
    if (blockIdx.x < 2048) {
        const size_t i = ((size_t)blockIdx.x * 256 + threadIdx.x) * 4;
        float4 v = *(const float4*)(x + i);
        uint2 p;
        p.x = f2bf(v.x) | ((unsigned int)f2bf(v.y) << 16);
        p.y = f2bf(v.z) | ((unsigned int)f2bf(v.w) << 16);
        *(uint2*)(xb + i) = p;
        return;
    }
    __shared__ float t[32][33];
    int id = blockIdx.x - 2048;
    const float* src; int K, N, Ntiles; size_t doff;
    if (id < 320) {
        int w = id >> 6; id &= 63; K = 256; N = 256; Ntiles = 8;
        doff = (size_t)w * 65536;
        src = (w == 0) ? w0 : (w == 1) ? w1 : (w == 2) ? w2 : (w == 3) ? w3 : w4;
    } else if (id < 448) {
        id -= 320; K = 256; N = 512; Ntiles = 16; doff = 327680; src = w5;
    } else {
        id -= 448; K = 512; N = 256; Ntiles = 8;  doff = 458752; src = w6;
    }
    const int tk = id / Ntiles, tn = id % Ntiles;
    const int k0 = tk * 32, n0 = tn * 32;
    const int c = threadIdx.x & 31, r8 = threadIdx.x >> 5;
    for (int rr = r8; rr < 32; rr += 8)
        t[rr][c] = src[(size_t)(k0 + rr) * N + n0 + c];
    __syncthreads();
    for (int rr = r8; rr < 32; rr += 8)
        wt[doff + (size_t)(n0 + rr) * K + k0 + c] = f2bf(t[c][rr]);
}

// ---------------------------------------------------------------------------
// Projection MFMA GEMM with head-major scatter epilogue.
//   wsel 0 (lk): dst[b][h][x=i][a=j][d]   wsel 1 (rk): dst[b][h][a=i][y=j][d]
//   wsel 2 (lv): dst[b][h][x=i][a=j][d]   wsel 3 (rv): dst[b][h][y=j][a=i][d]
// grid = (16, 64)
// ---------------------------------------------------------------------------
__global__ __launch_bounds__(256)
void proj_mfma(const unsigned short* __restrict__ A, const unsigned short* __restrict__ WT,
               unsigned short* __restrict__ projT)
{
    const int lane = threadIdx.x & 63, wave = threadIdx.x >> 6;
    const int wsel = blockIdx.x >> 2;
    const int col0 = (blockIdx.x & 3) * 64;
    const int m0 = blockIdx.y * 128 + wave * 32;
    const int lm = lane & 15, lk8 = (lane >> 4) * 8;
    const unsigned short* W = WT + (size_t)wsel * 65536;
    unsigned short* dst = projT + (size_t)wsel * 2097152;

    f4 acc[2][4];
    #pragma unroll
    for (int i = 0; i < 2; ++i)
        #pragma unroll
        for (int j = 0; j < 4; ++j) acc[i][j] = (f4){0.f, 0.f, 0.f, 0.f};

    for (int kc = 0; kc < 256; kc += 32) {
        short8 af[2], bf[4];
        #pragma unroll
        for (int i = 0; i < 2; ++i)
            af[i] = *(const short8*)(A + (size_t)(m0 + i * 16 + lm) * 256 + kc + lk8);
        #pragma unroll
        for (int j = 0; j < 4; ++j)
            bf[j] = *(const short8*)(W + (size_t)(col0 + j * 16 + lm) * 256 + kc + lk8);
        #pragma unroll
        for (int i = 0; i < 2; ++i)
            #pragma unroll
            for (int j = 0; j < 4; ++j)
                acc[i][j] = __builtin_amdgcn_mfma_f32_16x16x32_bf16(af[i], bf[j], acc[i][j], 0, 0, 0);
    }

    const int rbase = (lane >> 4) * 4;
    const int swap = (wsel == 3);
    #pragma unroll
    for (int i = 0; i < 2; ++i)
        #pragma unroll
        for (int j = 0; j < 4; ++j) {
            const int c = col0 + j * 16 + lm;
            const int h = c >> 5, d = c & 31;
            #pragma unroll
            for (int r = 0; r < 4; ++r) {
                const int m = m0 + i * 16 + rbase + r;
                const int b = m >> 12, ii = (m >> 6) & 63, jj = m & 63;
                const int p = swap ? jj : ii;
                const int q = swap ? ii : jj;
                const size_t idx = ((((size_t)b * 8 + h) * 64 + p) * 64 + q) * 32 + d;
                dst[idx] = f2bf(acc[i][j][r]);
            }
        }
}

// ---------------------------------------------------------------------------
// Scores via MFMA: per (b,h), wave w handles a = a0 + w.
//   S_a[x,y] = sum_d lk[x,a,d]*rk[a,y,d] / sqrt(32), stored bf16 as
//   S[b][h][x][a][y]  (x stride 4096, a stride 64, y stride 1).
// lkT: [b][h][x][a][d]; rkT: [b][h][a][y][d].  grid = 256 (b,h,a/4), 256 thr.
// ---------------------------------------------------------------------------
__global__ __launch_bounds__(256)
void scores_mfma(const unsigned short* __restrict__ lkT, const unsigned short* __restrict__ rkT,
                 unsigned short* __restrict__ S)
{
    const int lane = threadIdx.x & 63, wave = threadIdx.x >> 6;
    const int bi = blockIdx.x;
    const int b = bi >> 7, h = (bi >> 4) & 7, a = (bi & 15) * 4 + wave;
    const size_t bh = (size_t)b * 8 + h;
    const int lm = lane & 15, lk8 = (lane >> 4) * 8;

    // A fragments: lk rows x = mt*16+lm at fixed a
    short8 af[4], bf[4];
    #pragma unroll
    for (int t = 0; t < 4; ++t) {
        af[t] = *(const short8*)(lkT + ((bh * 64 + (t * 16 + lm)) * 64 + a) * 32 + lk8);
        bf[t] = *(const short8*)(rkT + ((bh * 64 + a) * 64 + (t * 16 + lm)) * 32 + lk8);
    }
    const int rbase = (lane >> 4) * 4;
    unsigned short* Sb = S + bh * 262144 + a * 64;   // + x*4096 + y
    #pragma unroll
    for (int mt = 0; mt < 4; ++mt)
        #pragma unroll
        for (int nt = 0; nt < 4; ++nt) {
            f4 acc = (f4){0.f, 0.f, 0.f, 0.f};
            acc = __builtin_amdgcn_mfma_f32_16x16x32_bf16(af[mt], bf[nt], acc, 0, 0, 0);
            #pragma unroll
            for (int r = 0; r < 4; ++r) {
                const int xx = mt * 16 + rbase + r;
                const int yy = nt * 16 + lm;
                Sb[(size_t)xx * 4096 + yy] = f2bf(acc[r] * 0.17677669529663687f);
            }
        }
}

// ---------------------------------------------------------------------------
// Softmax over a + aggregation, block per (b,h,x), 256 thr.
//   att[a,y] = softmax_a(S[b,h,x,a,y]);  o[y,d] = (1/L) sum_a att*lv[x,a,d]*rv[a,y,d]
// lvT: [b][h][x][a][d], rvT: [b][h][y][a][d].
// obuf[(b*64+x)*64+y][h*32+d] bf16.  grid = 1024.
// ---------------------------------------------------------------------------
__global__ __launch_bounds__(256)
void softmax_agg(const unsigned short* __restrict__ S, const unsigned short* __restrict__ lvT,
                 const unsigned short* __restrict__ rvT, unsigned short* __restrict__ obuf)
{
    __shared__ float att[64][64];           // [a][y]
    __shared__ float lvL[64][32];
    __shared__ float smx[4][64], ssm[4][64], invL[64];
    const int bi = blockIdx.x;
    const int b = bi >> 9, h = (bi >> 6) & 7, x = bi & 63;
    const size_t bh = (size_t)b * 8 + h;
    const int tid = threadIdx.x;

    {   // load S[x] slice (8KB bf16, contiguous) -> att f32 ; stage lv -> f32
        const int a = tid >> 2, yo = (tid & 3) * 16;
        const unsigned short* Sp = S + (bh * 64 + x) * 4096 + a * 64 + yo;
        uint4 p0 = *(const uint4*)(Sp);
        uint4 p1 = *(const uint4*)(Sp + 8);
        att[a][yo +  0] = bf2f(p0.x); att[a][yo +  1] = bf2f(p0.x >> 16);
        att[a][yo +  2] = bf2f(p0.y); att[a][yo +  3] = bf2f(p0.y >> 16);
        att[a][yo +  4] = bf2f(p0.z); att[a][yo +  5] = bf2f(p0.z >> 16);
        att[a][yo +  6] = bf2f(p0.w); att[a][yo +  7] = bf2f(p0.w >> 16);
        att[a][yo +  8] = bf2f(p1.x); att[a][yo +  9] = bf2f(p1.x >> 16);
        att[a][yo + 10] = bf2f(p1.y); att[a][yo + 11] = bf2f(p1.y >> 16);
        att[a][yo + 12] = bf2f(p1.z); att[a][yo + 13] = bf2f(p1.z >> 16);
        att[a][yo + 14] = bf2f(p1.w); att[a][yo + 15] = bf2f(p1.w >> 16);
        const int d0 = (tid & 3) * 8;
        uint4 q = *(const uint4*)(lvT + ((bh * 64 + x) * 64 + a) * 32 + d0);
        lvL[a][d0 + 0] = bf2f(q.x); lvL[a][d0 + 1] = bf2f(q.x >> 16);
        lvL[a][d0 + 2] = bf2f(q.y); lvL[a][d0 + 3] = bf2f(q.y >> 16);
        lvL[a][d0 + 4] = bf2f(q.z); lvL[a][d0 + 5] = bf2f(q.z >> 16);
        lvL[a][d0 + 6] = bf2f(q.w); lvL[a][d0 + 7] = bf2f(q.w >> 16);
    }
    __syncthreads();

    {   // per-slice max over a
        const int y = tid & 63, az = tid >> 6;
        float mx = -1e30f;
        for (int a = az; a < 64; a += 4) mx = fmaxf(mx, att[a][y]);
        smx[az][y] = mx;
    }
    __syncthreads();

    {   // exp + partial sums
        const int y = tid & 63, az = tid >> 6;
        const float mx = fmaxf(fmaxf(smx[0][y], smx[1][y]), fmaxf(smx[2][y], smx[3][y]));
        float s = 0.f;
        for (int a = az; a < 64; a += 4) {
            float e = __expf(att[a][y] - mx);
            att[a][y] = e;
            s += e;
        }
        ssm[az][y] = s;
    }
    __syncthreads();
    if (tid < 64)
        invL[tid] = 1.f / (ssm[0][tid] + ssm[1][tid] + ssm[2][tid] + ssm[3][tid]);
    __syncthreads();

    {   // aggregation; thread = (dp = d-pair, yb); y = yb + 16*it
        const int dp = tid & 15, yb = tid >> 4;
        #pragma unroll
        for (int it = 0; it < 4; ++it) {
            const int y = yb + it * 16;
            const unsigned short* rvr = rvT + (bh * 64 + y) * 2048 + dp * 2;
            float a0 = 0.f, a1 = 0.f;
            #pragma unroll 8
            for (int a = 0; a < 64; ++a) {
                unsigned int pk = *(const unsigned int*)(rvr + a * 32);
                float w = att[a][y];
                a0 += w * lvL[a][2 * dp]     * bf2f(pk);
                a1 += w * lvL[a][2 * dp + 1] * bf2f(pk >> 16);
            }
            const float inv = invL[y];
            a0 *= inv; a1 *= inv;
            unsigned int st = f2bf(a0) | ((unsigned int)f2bf(a1) << 16);
            *(unsigned int*)(obuf + (((size_t)b * 64 + x) * 64 + y) * 256 + h * 32 + dp * 2) = st;
        }
    }
}

// ---------------------------------------------------------------------------
// FFN1: out = relu( A(8192x256 bf16) @ WT(512x256)^T + bias ), bf16 out.
// tile 128x64 (wave = 32 rows x 64 cols), grid = (8, 64).   [round-5 version]
// ---------------------------------------------------------------------------
__global__ __launch_bounds__(256)
void gemm_mfma(const unsigned short* __restrict__ A, const unsigned short* __restrict__ WT,
               const float* __restrict__ bias, unsigned short* __restrict__ outB,
               int K, int N)
{
    const int lane = threadIdx.x & 63, wave = threadIdx.x >> 6;
    const int m0 = blockIdx.y * 128 + wave * 32;
    const int col0 = blockIdx.x * 64;
    const int lm = lane & 15, lk8 = (lane >> 4) * 8;

    f4 acc[2][4];
    #pragma unroll
    for (int i = 0; i < 2; ++i)
        #pragma unroll
        for (int j = 0; j < 4; ++j) acc[i][j] = (f4){0.f, 0.f, 0.f, 0.f};

    for (int kc = 0; kc < K; kc += 32) {
        short8 af[2], bf[4];
        #pragma unroll
        for (int i = 0; i < 2; ++i)
            af[i] = *(const short8*)(A + (size_t)(m0 + i * 16 + lm) * K + kc + lk8);
        #pragma unroll
        for (int j = 0; j < 4; ++j)
            bf[j] = *(const short8*)(WT + (size_t)(col0 + j * 16 + lm) * K + kc + lk8);
        #pragma unroll
        for (int i = 0; i < 2; ++i)
            #pragma unroll
            for (int j = 0; j < 4; ++j)
                acc[i][j] = __builtin_amdgcn_mfma_f32_16x16x32_bf16(af[i], bf[j], acc[i][j], 0, 0, 0);
    }

    const int rbase = (lane >> 4) * 4;
    #pragma unroll
    for (int i = 0; i < 2; ++i)
        #pragma unroll
        for (int j = 0; j < 4; ++j) {
            const int n = col0 + j * 16 + lm;
            const float bb = bias[n];
            #pragma unroll
            for (int r = 0; r < 4; ++r) {
                const int m = m0 + i * 16 + rbase + r;
                outB[(size_t)m * N + n] = f2bf(fmaxf(acc[i][j][r] + bb, 0.f));
            }
        }
}

// ---------------------------------------------------------------------------
// Fused GEMM + residual + LayerNorm (round-5 version, 256 thr).
// tile: 16 rows x 256 cols; 4 waves, wave w covers cols w*64..+63.
//   t = A @ WT^T [+ bias] + resid ;  out = LN(t) * gamma + beta
// mode 0: write outF (fp32) and outB (bf16).  mode 1: write outF only.
// grid = 512 (8192/16).
// ---------------------------------------------------------------------------
__global__ __launch_bounds__(256)
void gemm_ln(const unsigned short* __restrict__ A, const unsigned short* __restrict__ WT,
             const float* __restrict__ bias, const float* __restrict__ resid,
             const float* __restrict__ gamma, const float* __restrict__ beta,
             float* __restrict__ outF, unsigned short* __restrict__ outB,
             int K, int mode)
{
    __shared__ float ps[16][4], pq[16][4];
    const int lane = threadIdx.x & 63, wave = threadIdx.x >> 6;
    const int m0 = blockIdx.x * 16;
    const int col0 = wave * 64;
    const int lm = lane & 15, lk8 = (lane >> 4) * 8;

    f4 acc[4];
    #pragma unroll
    for (int j = 0; j < 4; ++j) acc[j] = (f4){0.f, 0.f, 0.f, 0.f};

    for (int kc = 0; kc < K; kc += 32) {
        short8 af = *(const short8*)(A + (size_t)(m0 + lm) * K + kc + lk8);
        #pragma unroll
        for (int j = 0; j < 4; ++j) {
            short8 bf = *(const short8*)(WT + (size_t)(col0 + j * 16 + lm) * K + kc + lk8);
            acc[j] = __builtin_amdgcn_mfma_f32_16x16x32_bf16(af, bf, acc[j], 0, 0, 0);
        }
    }

    const int rbase = (lane >> 4) * 4;
    float v[4][4];
    float s[4] = {0.f, 0.f, 0.f, 0.f}, q[4] = {0.f, 0.f, 0.f, 0.f};
    #pragma unroll
    for (int j = 0; j < 4; ++j) {
        const int n = col0 + j * 16 + lm;
        const float bb = bias ? bias[n] : 0.f;
        #pragma unroll
        for (int r = 0; r < 4; ++r) {
            const int m = m0 + rbase + r;
            float t = acc[j][r] + bb + resid[(size_t)m * 256 + n];
            v[j][r] = t;
            s[r] += t;
            q[r] += t * t;
        }
    }
    #pragma unroll
    for (int off = 1; off < 16; off <<= 1) {
        #pragma unroll
        for (int r = 0; r < 4; ++r) {
            s[r] += __shfl_xor(s[r], off);
            q[r] += __shfl_xor(q[r], off);
        }
    }
    if (lm == 0) {
        #pragma unroll
        for (int r = 0; r < 4; ++r) {
            ps[rbase + r][wave] = s[r];
            pq[rbase + r][wave] = q[r];
        }
    }
    __syncthreads();
    #pragma unroll
    for (int r = 0; r < 4; ++r) {
        const int lr = rbase + r;
        const float Sm = ps[lr][0] + ps[lr][1] + ps[lr][2] + ps[lr][3];
        const float Qm = pq[lr][0] + pq[lr][1] + pq[lr][2] + pq[lr][3];
        const float mu = Sm * (1.f / 256.f);
        const float ri = rsqrtf(Qm * (1.f / 256.f) - mu * mu + 1e-5f);
        const int m = m0 + lr;
        #pragma unroll
        for (int j = 0; j < 4; ++j) {
            const int n = col0 + j * 16 + lm;
            const float rv = (v[j][r] - mu) * ri * gamma[n] + beta[n];
            outF[(size_t)m * 256 + n] = rv;
            if (mode == 0) outB[(size_t)m * 256 + n] = f2bf(rv);
        }
    }
}

// ---------------------------------------------------------------------------
extern "C" void kernel_launch(void* const* d_in, const int* in_sizes, int n_in,
                              void* d_out, int out_size, void* d_ws, size_t ws_size,
                              hipStream_t stream)
{
    const float* x    = (const float*)d_in[0];
    const float* Wlk  = (const float*)d_in[1];
    const float* Wrk  = (const float*)d_in[2];
    const float* Wlv  = (const float*)d_in[3];
    const float* Wrv  = (const float*)d_in[4];
    const float* Wout = (const float*)d_in[5];
    const float* g1   = (const float*)d_in[6];
    const float* be1  = (const float*)d_in[7];
    const float* W1   = (const float*)d_in[8];
    const float* b1   = (const float*)d_in[9];
    const float* W2   = (const float*)d_in[10];
    const float* b2   = (const float*)d_in[11];
    const float* g2   = (const float*)d_in[12];
    const float* be2  = (const float*)d_in[13];

    char* base = (char*)d_ws;
    const size_t MB = 1ull << 20;
    unsigned short* xb    = (unsigned short*)(base + 0);        // 4MB; reused as obuf
    unsigned short* obufb = (unsigned short*)(base + 0);
    unsigned short* projT = (unsigned short*)(base + 4 * MB);   // lkT,rkT,lvT,rvT 4x4MB
    unsigned short* lkT   = projT;
    unsigned short* rkT   = projT + 2097152;
    unsigned short* lvT   = projT + 2 * 2097152;
    unsigned short* rvT   = projT + 3 * 2097152;
    float*          hf    = (float*)(base + 20 * MB);           // 8MB
    unsigned short* hb    = (unsigned short*)(base + 28 * MB);  // 4MB
    unsigned short* midb  = (unsigned short*)(base + 36 * MB);  // 8MB
    unsigned short* Sbuf  = (unsigned short*)(base + 44 * MB);  // 8MB bf16 scores
    unsigned short* WT    = (unsigned short*)(base + 52 * MB);  // 1.2MB

    // 1. casts (x -> bf16, weights -> transposed bf16)
    cast_all<<<2624, 256, 0, stream>>>(x, xb, Wlk, Wrk, Wlv, Wrv, Wout, W1, W2, WT);
    // 2. projections + head-major scatter
    proj_mfma<<<dim3(16, 64), 256, 0, stream>>>(xb, WT, projT);
    // 3. scores via MFMA -> S (bf16)
    scores_mfma<<<256, 256, 0, stream>>>(lkT, rkT, Sbuf);
    // 4. softmax + aggregation -> obuf (bf16)
    softmax_agg<<<1024, 256, 0, stream>>>(Sbuf, lvT, rvT, obufb);
    // 5. h = LN(x + obuf @ W_out) -> hf (fp32) + hb (bf16)
    gemm_ln<<<512, 256, 0, stream>>>(obufb, WT + 262144, nullptr, x, g1, be1, hf, hb, 256, 0);
    // 6. midb = relu(hb @ W1 + b1) (bf16)
    gemm_mfma<<<dim3(8, 64), 256, 0, stream>>>(hb, WT + 327680, b1, midb, 256, 512);
    // 7. out = LN(hf + midb @ W2 + b2) -> fp32 d_out
    gemm_ln<<<512, 256, 0, stream>>>(midb, WT + 458752, b2, hf, g2, be2, (float*)d_out, nullptr, 512, 1);
}

// Round 10
// 187.240 us; speedup vs baseline: 1.4818x; 1.0356x over previous
//
#include <hip/hip_runtime.h>

// B=2, N=64, D=256, H=8, DK=32.  ROWS = B*N*N = 8192.
#define ROWS 8192
#define DIM  256

typedef short short8 __attribute__((ext_vector_type(8)));
typedef float f4     __attribute__((ext_vector_type(4)));

__device__ __forceinline__ float bf2f(unsigned int u16) {
    union { unsigned int i; float f; } v;
    v.i = (u16 & 0xffffu) << 16;
    return v.f;
}
__device__ __forceinline__ unsigned short f2bf(float f) {
    union { float f; unsigned int u; } v; v.f = f;
    unsigned int r = v.u + 0x7fffu + ((v.u >> 16) & 1u);   // RNE
    return (unsigned short)(r >> 16);
}

// ---------------------------------------------------------------------------
// Merged casts. Blocks [0,2048): x(8192x256 fp32)->xb bf16.
// Blocks [2048,2624): weights -> WT[n][k] bf16 packed.
//   w0..w4 at w*65536 ; W1(256x512)->512x256 @327680 ; W2(512x256)->256x512 @458752
// ---------------------------------------------------------------------------
__global__ __launch_bounds__(256)
void cast_all(const float* __restrict__ x, unsigned short* __restrict__ xb,
              const float* __restrict__ w0, const float* __restrict__ w1,
              const float* __restrict__ w2, const float* __restrict__ w3,
              const float* __restrict__ w4, const float* __restrict__ w5,
              const float* __restrict__ w6, unsigned short* __restrict__ wt)
{
    if (blockIdx.x < 2048) {
        const size_t i = ((size_t)blockIdx.x * 256 + threadIdx.x) * 4;
        float4 v = *(const float4*)(x + i);
        uint2 p;
        p.x = f2bf(v.x) | ((unsigned int)f2bf(v.y) << 16);
        p.y = f2bf(v.z) | ((unsigned int)f2bf(v.w) << 16);
        *(uint2*)(xb + i) = p;
        return;
    }
    __shared__ float t[32][33];
    int id = blockIdx.x - 2048;
    const float* src; int K, N, Ntiles; size_t doff;
    if (id < 320) {
        int w = id >> 6; id &= 63; K = 256; N = 256; Ntiles = 8;
        doff = (size_t)w * 65536;
        src = (w == 0) ? w0 : (w == 1) ? w1 : (w == 2) ? w2 : (w == 3) ? w3 : w4;
    } else if (id < 448) {
        id -= 320; K = 256; N = 512; Ntiles = 16; doff = 327680; src = w5;
    } else {
        id -= 448; K = 512; N = 256; Ntiles = 8;  doff = 458752; src = w6;
    }
    const int tk = id / Ntiles, tn = id % Ntiles;
    const int k0 = tk * 32, n0 = tn * 32;
    const int c = threadIdx.x & 31, r8 = threadIdx.x >> 5;
    for (int rr = r8; rr < 32; rr += 8)
        t[rr][c] = src[(size_t)(k0 + rr) * N + n0 + c];
    __syncthreads();
    for (int rr = r8; rr < 32; rr += 8)
        wt[doff + (size_t)(n0 + rr) * K + k0 + c] = f2bf(t[c][rr]);
}

// ---------------------------------------------------------------------------
// Projection MFMA GEMM with head-major scatter epilogue.
//   wsel 0 (lk): dst[b][h][x=i][a=j][d]   wsel 1 (rk): dst[b][h][a=i][y=j][d]
//   wsel 2 (lv): dst[b][h][x=i][a=j][d]   wsel 3 (rv): dst[b][h][y=j][a=i][d]
// grid = (16, 64)
// ---------------------------------------------------------------------------
__global__ __launch_bounds__(256)
void proj_mfma(const unsigned short* __restrict__ A, const unsigned short* __restrict__ WT,
               unsigned short* __restrict__ projT)
{
    const int lane = threadIdx.x & 63, wave = threadIdx.x >> 6;
    const int wsel = blockIdx.x >> 2;
    const int col0 = (blockIdx.x & 3) * 64;
    const int m0 = blockIdx.y * 128 + wave * 32;
    const int lm = lane & 15, lk8 = (lane >> 4) * 8;
    const unsigned short* W = WT + (size_t)wsel * 65536;
    unsigned short* dst = projT + (size_t)wsel * 2097152;

    f4 acc[2][4];
    #pragma unroll
    for (int i = 0; i < 2; ++i)
        #pragma unroll
        for (int j = 0; j < 4; ++j) acc[i][j] = (f4){0.f, 0.f, 0.f, 0.f};

    #pragma unroll 2
    for (int kc = 0; kc < 256; kc += 32) {
        short8 af[2], bf[4];
        #pragma unroll
        for (int i = 0; i < 2; ++i)
            af[i] = *(const short8*)(A + (size_t)(m0 + i * 16 + lm) * 256 + kc + lk8);
        #pragma unroll
        for (int j = 0; j < 4; ++j)
            bf[j] = *(const short8*)(W + (size_t)(col0 + j * 16 + lm) * 256 + kc + lk8);
        #pragma unroll
        for (int i = 0; i < 2; ++i)
            #pragma unroll
            for (int j = 0; j < 4; ++j)
                acc[i][j] = __builtin_amdgcn_mfma_f32_16x16x32_bf16(af[i], bf[j], acc[i][j], 0, 0, 0);
    }

    const int rbase = (lane >> 4) * 4;
    const int swap = (wsel == 3);
    #pragma unroll
    for (int i = 0; i < 2; ++i)
        #pragma unroll
        for (int j = 0; j < 4; ++j) {
            const int c = col0 + j * 16 + lm;
            const int h = c >> 5, d = c & 31;
            #pragma unroll
            for (int r = 0; r < 4; ++r) {
                const int m = m0 + i * 16 + rbase + r;
                const int b = m >> 12, ii = (m >> 6) & 63, jj = m & 63;
                const int p = swap ? jj : ii;
                const int q = swap ? ii : jj;
                const size_t idx = ((((size_t)b * 8 + h) * 64 + p) * 64 + q) * 32 + d;
                dst[idx] = f2bf(acc[i][j][r]);
            }
        }
}

// ---------------------------------------------------------------------------
// Scores via MFMA: per (b,h), wave w handles a = a0 + w.
//   S_a[x,y] = sum_d lk[x,a,d]*rk[a,y,d] / sqrt(32), stored bf16 as
//   S[b][h][x][a][y].  grid = 256 (b,h,a/4), 256 thr.
// ---------------------------------------------------------------------------
__global__ __launch_bounds__(256)
void scores_mfma(const unsigned short* __restrict__ lkT, const unsigned short* __restrict__ rkT,
                 unsigned short* __restrict__ S)
{
    const int lane = threadIdx.x & 63, wave = threadIdx.x >> 6;
    const int bi = blockIdx.x;
    const int b = bi >> 7, h = (bi >> 4) & 7, a = (bi & 15) * 4 + wave;
    const size_t bh = (size_t)b * 8 + h;
    const int lm = lane & 15, lk8 = (lane >> 4) * 8;

    short8 af[4], bf[4];
    #pragma unroll
    for (int t = 0; t < 4; ++t) {
        af[t] = *(const short8*)(lkT + ((bh * 64 + (t * 16 + lm)) * 64 + a) * 32 + lk8);
        bf[t] = *(const short8*)(rkT + ((bh * 64 + a) * 64 + (t * 16 + lm)) * 32 + lk8);
    }
    const int rbase = (lane >> 4) * 4;
    unsigned short* Sb = S + bh * 262144 + a * 64;   // + x*4096 + y
    #pragma unroll
    for (int mt = 0; mt < 4; ++mt)
        #pragma unroll
        for (int nt = 0; nt < 4; ++nt) {
            f4 acc = (f4){0.f, 0.f, 0.f, 0.f};
            acc = __builtin_amdgcn_mfma_f32_16x16x32_bf16(af[mt], bf[nt], acc, 0, 0, 0);
            #pragma unroll
            for (int r = 0; r < 4; ++r) {
                const int xx = mt * 16 + rbase + r;
                const int yy = nt * 16 + lm;
                Sb[(size_t)xx * 4096 + yy] = f2bf(acc[r] * 0.17677669529663687f);
            }
        }
}

// ---------------------------------------------------------------------------
// Softmax over a + aggregation, block per (b,h,x), 256 thr.
// Explicit fmaf in the hot loop (no -ffast-math: a*b+c otherwise = mul+add).
// obuf[(b*64+x)*64+y][h*32+d] bf16.  grid = 1024.
// ---------------------------------------------------------------------------
__global__ __launch_bounds__(256)
void softmax_agg(const unsigned short* __restrict__ S, const unsigned short* __restrict__ lvT,
                 const unsigned short* __restrict__ rvT, unsigned short* __restrict__ obuf)
{
    __shared__ float att[64][64];           // [a][y]
    __shared__ float lvL[64][32];
    __shared__ float smx[4][64], ssm[4][64], invL[64];
    const int bi = blockIdx.x;
    const int b = bi >> 9, h = (bi >> 6) & 7, x = bi & 63;
    const size_t bh = (size_t)b * 8 + h;
    const int tid = threadIdx.x;

    {   // load S[x] slice (8KB bf16, contiguous) -> att f32 ; stage lv -> f32
        const int a = tid >> 2, yo = (tid & 3) * 16;
        const unsigned short* Sp = S + (bh * 64 + x) * 4096 + a * 64 + yo;
        uint4 p0 = *(const uint4*)(Sp);
        uint4 p1 = *(const uint4*)(Sp + 8);
        att[a][yo +  0] = bf2f(p0.x); att[a][yo +  1] = bf2f(p0.x >> 16);
        att[a][yo +  2] = bf2f(p0.y); att[a][yo +  3] = bf2f(p0.y >> 16);
        att[a][yo +  4] = bf2f(p0.z); att[a][yo +  5] = bf2f(p0.z >> 16);
        att[a][yo +  6] = bf2f(p0.w); att[a][yo +  7] = bf2f(p0.w >> 16);
        att[a][yo +  8] = bf2f(p1.x); att[a][yo +  9] = bf2f(p1.x >> 16);
        att[a][yo + 10] = bf2f(p1.y); att[a][yo + 11] = bf2f(p1.y >> 16);
        att[a][yo + 12] = bf2f(p1.z); att[a][yo + 13] = bf2f(p1.z >> 16);
        att[a][yo + 14] = bf2f(p1.w); att[a][yo + 15] = bf2f(p1.w >> 16);
        const int d0 = (tid & 3) * 8;
        uint4 q = *(const uint4*)(lvT + ((bh * 64 + x) * 64 + a) * 32 + d0);
        lvL[a][d0 + 0] = bf2f(q.x); lvL[a][d0 + 1] = bf2f(q.x >> 16);
        lvL[a][d0 + 2] = bf2f(q.y); lvL[a][d0 + 3] = bf2f(q.y >> 16);
        lvL[a][d0 + 4] = bf2f(q.z); lvL[a][d0 + 5] = bf2f(q.z >> 16);
        lvL[a][d0 + 6] = bf2f(q.w); lvL[a][d0 + 7] = bf2f(q.w >> 16);
    }
    __syncthreads();

    {   // per-slice max over a
        const int y = tid & 63, az = tid >> 6;
        float mx = -1e30f;
        for (int a = az; a < 64; a += 4) mx = fmaxf(mx, att[a][y]);
        smx[az][y] = mx;
    }
    __syncthreads();

    {   // exp + partial sums
        const int y = tid & 63, az = tid >> 6;
        const float mx = fmaxf(fmaxf(smx[0][y], smx[1][y]), fmaxf(smx[2][y], smx[3][y]));
        float s = 0.f;
        for (int a = az; a < 64; a += 4) {
            float e = __expf(att[a][y] - mx);
            att[a][y] = e;
            s += e;
        }
        ssm[az][y] = s;
    }
    __syncthreads();
    if (tid < 64)
        invL[tid] = 1.f / (ssm[0][tid] + ssm[1][tid] + ssm[2][tid] + ssm[3][tid]);
    __syncthreads();

    {   // aggregation; thread = (dp = d-pair, yb); y = yb + 16*it
        const int dp = tid & 15, yb = tid >> 4;
        #pragma unroll
        for (int it = 0; it < 4; ++it) {
            const int y = yb + it * 16;
            const unsigned short* rvr = rvT + (bh * 64 + y) * 2048 + dp * 2;
            float a0 = 0.f, a1 = 0.f;
            #pragma unroll 8
            for (int a = 0; a < 64; ++a) {
                unsigned int pk = *(const unsigned int*)(rvr + a * 32);
                float w = att[a][y];
                a0 = fmaf(w * lvL[a][2 * dp],     bf2f(pk),       a0);
                a1 = fmaf(w * lvL[a][2 * dp + 1], bf2f(pk >> 16), a1);
            }
            const float inv = invL[y];
            a0 *= inv; a1 *= inv;
            unsigned int st = f2bf(a0) | ((unsigned int)f2bf(a1) << 16);
            *(unsigned int*)(obuf + (((size_t)b * 64 + x) * 64 + y) * 256 + h * 32 + dp * 2) = st;
        }
    }
}

// ---------------------------------------------------------------------------
// FFN1: out = relu( A(8192x256 bf16) @ WT(512x256)^T + bias ), bf16 out.
// Compile-time K/N so the K-loop unrolls & pipelines.
// tile 128x64 (wave = 32 rows x 64 cols), grid = (8, 64).
// ---------------------------------------------------------------------------
__global__ __launch_bounds__(256)
void gemm_ffn1(const unsigned short* __restrict__ A, const unsigned short* __restrict__ WT,
               const float* __restrict__ bias, unsigned short* __restrict__ outB)
{
    constexpr int K = 256, N = 512;
    const int lane = threadIdx.x & 63, wave = threadIdx.x >> 6;
    const int m0 = blockIdx.y * 128 + wave * 32;
    const int col0 = blockIdx.x * 64;
    const int lm = lane & 15, lk8 = (lane >> 4) * 8;

    f4 acc[2][4];
    #pragma unroll
    for (int i = 0; i < 2; ++i)
        #pragma unroll
        for (int j = 0; j < 4; ++j) acc[i][j] = (f4){0.f, 0.f, 0.f, 0.f};

    #pragma unroll 2
    for (int kc = 0; kc < K; kc += 32) {
        short8 af[2], bf[4];
        #pragma unroll
        for (int i = 0; i < 2; ++i)
            af[i] = *(const short8*)(A + (size_t)(m0 + i * 16 + lm) * K + kc + lk8);
        #pragma unroll
        for (int j = 0; j < 4; ++j)
            bf[j] = *(const short8*)(WT + (size_t)(col0 + j * 16 + lm) * K + kc + lk8);
        #pragma unroll
        for (int i = 0; i < 2; ++i)
            #pragma unroll
            for (int j = 0; j < 4; ++j)
                acc[i][j] = __builtin_amdgcn_mfma_f32_16x16x32_bf16(af[i], bf[j], acc[i][j], 0, 0, 0);
    }

    const int rbase = (lane >> 4) * 4;
    #pragma unroll
    for (int i = 0; i < 2; ++i)
        #pragma unroll
        for (int j = 0; j < 4; ++j) {
            const int n = col0 + j * 16 + lm;
            const float bb = bias[n];
            #pragma unroll
            for (int r = 0; r < 4; ++r) {
                const int m = m0 + i * 16 + rbase + r;
                outB[(size_t)m * N + n] = f2bf(fmaxf(acc[i][j][r] + bb, 0.f));
            }
        }
}

// ---------------------------------------------------------------------------
// Fused GEMM + residual + LayerNorm, templated on K / residual dtype / out dtype.
// tile: 16 rows x 256 cols; 4 waves, wave w covers cols w*64..+63.
//   t = A @ WT^T [+ bias] + resid ;  out = LN(t) * gamma + beta
// grid = 512 (8192/16), 256 thr.
// ---------------------------------------------------------------------------
template<int K, bool RBF16, bool OBF16>
__global__ __launch_bounds__(256)
void gemm_ln_t(const unsigned short* __restrict__ A, const unsigned short* __restrict__ WT,
               const float* __restrict__ bias, const void* __restrict__ resid,
               const float* __restrict__ gamma, const float* __restrict__ beta,
               void* __restrict__ out)
{
    __shared__ float ps[16][4], pq[16][4];
    const int lane = threadIdx.x & 63, wave = threadIdx.x >> 6;
    const int m0 = blockIdx.x * 16;
    const int col0 = wave * 64;
    const int lm = lane & 15, lk8 = (lane >> 4) * 8;

    f4 acc[4];
    #pragma unroll
    for (int j = 0; j < 4; ++j) acc[j] = (f4){0.f, 0.f, 0.f, 0.f};

    #pragma unroll 2
    for (int kc = 0; kc < K; kc += 32) {
        short8 af = *(const short8*)(A + (size_t)(m0 + lm) * K + kc + lk8);
        #pragma unroll
        for (int j = 0; j < 4; ++j) {
            short8 bf = *(const short8*)(WT + (size_t)(col0 + j * 16 + lm) * K + kc + lk8);
            acc[j] = __builtin_amdgcn_mfma_f32_16x16x32_bf16(af, bf, acc[j], 0, 0, 0);
        }
    }

    const int rbase = (lane >> 4) * 4;
    float v[4][4];
    float s[4] = {0.f, 0.f, 0.f, 0.f}, q[4] = {0.f, 0.f, 0.f, 0.f};
    #pragma unroll
    for (int j = 0; j < 4; ++j) {
        const int n = col0 + j * 16 + lm;
        const float bb = bias ? bias[n] : 0.f;
        #pragma unroll
        for (int r = 0; r < 4; ++r) {
            const int m = m0 + rbase + r;
            const size_t idx = (size_t)m * 256 + n;
            const float rr = RBF16 ? bf2f(((const unsigned short*)resid)[idx])
                                   : ((const float*)resid)[idx];
            float t = acc[j][r] + bb + rr;
            v[j][r] = t;
            s[r] += t;
            q[r] = fmaf(t, t, q[r]);
        }
    }
    #pragma unroll
    for (int off = 1; off < 16; off <<= 1) {
        #pragma unroll
        for (int r = 0; r < 4; ++r) {
            s[r] += __shfl_xor(s[r], off);
            q[r] += __shfl_xor(q[r], off);
        }
    }
    if (lm == 0) {
        #pragma unroll
        for (int r = 0; r < 4; ++r) {
            ps[rbase + r][wave] = s[r];
            pq[rbase + r][wave] = q[r];
        }
    }
    __syncthreads();
    #pragma unroll
    for (int r = 0; r < 4; ++r) {
        const int lr = rbase + r;
        const float Sm = ps[lr][0] + ps[lr][1] + ps[lr][2] + ps[lr][3];
        const float Qm = pq[lr][0] + pq[lr][1] + pq[lr][2] + pq[lr][3];
        const float mu = Sm * (1.f / 256.f);
        const float ri = rsqrtf(Qm * (1.f / 256.f) - mu * mu + 1e-5f);
        const int m = m0 + lr;
        #pragma unroll
        for (int j = 0; j < 4; ++j) {
            const int n = col0 + j * 16 + lm;
            const size_t idx = (size_t)m * 256 + n;
            const float rv = (v[j][r] - mu) * ri * gamma[n] + beta[n];
            if (OBF16) ((unsigned short*)out)[idx] = f2bf(rv);
            else       ((float*)out)[idx] = rv;
        }
    }
}

// ---------------------------------------------------------------------------
extern "C" void kernel_launch(void* const* d_in, const int* in_sizes, int n_in,
                              void* d_out, int out_size, void* d_ws, size_t ws_size,
                              hipStream_t stream)
{
    const float* x    = (const float*)d_in[0];
    const float* Wlk  = (const float*)d_in[1];
    const float* Wrk  = (const float*)d_in[2];
    const float* Wlv  = (const float*)d_in[3];
    const float* Wrv  = (const float*)d_in[4];
    const float* Wout = (const float*)d_in[5];
    const float* g1   = (const float*)d_in[6];
    const float* be1  = (const float*)d_in[7];
    const float* W1   = (const float*)d_in[8];
    const float* b1   = (const float*)d_in[9];
    const float* W2   = (const float*)d_in[10];
    const float* b2   = (const float*)d_in[11];
    const float* g2   = (const float*)d_in[12];
    const float* be2  = (const float*)d_in[13];

    char* base = (char*)d_ws;
    const size_t MB = 1ull << 20;
    unsigned short* xb    = (unsigned short*)(base + 0);        // 4MB; reused as obuf
    unsigned short* obufb = (unsigned short*)(base + 0);
    unsigned short* projT = (unsigned short*)(base + 4 * MB);   // lkT,rkT,lvT,rvT 4x4MB
    unsigned short* lkT   = projT;
    unsigned short* rkT   = projT + 2097152;
    unsigned short* lvT   = projT + 2 * 2097152;
    unsigned short* rvT   = projT + 3 * 2097152;
    unsigned short* hb    = (unsigned short*)(base + 20 * MB);  // 4MB bf16 h
    unsigned short* midb  = (unsigned short*)(base + 24 * MB);  // 8MB
    unsigned short* Sbuf  = (unsigned short*)(base + 32 * MB);  // 8MB bf16 scores
    unsigned short* WT    = (unsigned short*)(base + 40 * MB);  // 1.2MB

    // 1. casts (x -> bf16, weights -> transposed bf16)
    cast_all<<<2624, 256, 0, stream>>>(x, xb, Wlk, Wrk, Wlv, Wrv, Wout, W1, W2, WT);
    // 2. projections + head-major scatter
    proj_mfma<<<dim3(16, 64), 256, 0, stream>>>(xb, WT, projT);
    // 3. scores via MFMA -> S (bf16)
    scores_mfma<<<256, 256, 0, stream>>>(lkT, rkT, Sbuf);
    // 4. softmax + aggregation -> obuf (bf16)
    softmax_agg<<<1024, 256, 0, stream>>>(Sbuf, lvT, rvT, obufb);
    // 5. h = LN(x + obuf @ W_out) -> hb (bf16)
    gemm_ln_t<256, false, true><<<512, 256, 0, stream>>>(obufb, WT + 262144, nullptr, x, g1, be1, hb);
    // 6. midb = relu(hb @ W1 + b1) (bf16)
    gemm_ffn1<<<dim3(8, 64), 256, 0, stream>>>(hb, WT + 327680, b1, midb);
    // 7. out = LN(hb + midb @ W2 + b2) -> fp32 d_out
    gemm_ln_t<512, true, false><<<512, 256, 0, stream>>>(midb, WT + 458752, b2, hb, g2, be2, (float*)d_out);
}